// Round 1
// 1525.731 us; speedup vs baseline: 1.0989x; 1.0989x over previous
//
#include <hip/hip_runtime.h>

#define B_   128
#define NO_  256
#define NR_  512
#define D_   1024

typedef __bf16 bf16x8 __attribute__((ext_vector_type(8)));
typedef float  f32x4  __attribute__((ext_vector_type(4)));

__device__ __forceinline__ unsigned short f2b(float f){   // fp32 -> bf16 RNE
  unsigned int u = __float_as_uint(f);
  unsigned int r = (u + 0x7fffu + ((u >> 16) & 1u)) >> 16;
  return (unsigned short)r;
}

// ---------------- fp32 -> bf16 flat convert (8 elems/thread) ----------------
__global__ void conv_f32_bf16(const float4* __restrict__ in, uint4* __restrict__ out, int n8){
  int i = blockIdx.x * blockDim.x + threadIdx.x;
  if (i >= n8) return;
  float4 a = in[2*i], b = in[2*i+1];
  union { unsigned short s[8]; uint4 v; } p;
  p.s[0]=f2b(a.x); p.s[1]=f2b(a.y); p.s[2]=f2b(a.z); p.s[3]=f2b(a.w);
  p.s[4]=f2b(b.x); p.s[5]=f2b(b.y); p.s[6]=f2b(b.z); p.s[7]=f2b(b.w);
  out[i] = p.v;
}

// ---------------- copy fp32 obj -> out0 (uint4 = 4 floats) ----------------
__global__ void copy_vec4(const uint4* __restrict__ in, uint4* __restrict__ out, int n){
  int i = blockIdx.x * blockDim.x + threadIdx.x;
  if (i < n) out[i] = in[i];
}

// ---------------- transpose + convert: fp32 [R][C] -> bf16 [C][R] ----------------
__global__ void transpose_f32_bf16(const float* __restrict__ in,
                                   unsigned short* __restrict__ out, int R, int C){
  __shared__ unsigned short tile[32][33];
  int tx = threadIdx.x, ty = threadIdx.y;       // 32 x 8
  int x  = blockIdx.x * 32 + tx;
  int y0 = blockIdx.y * 32;
  #pragma unroll
  for (int i = 0; i < 4; i++) tile[ty + i*8][tx] = f2b(in[(size_t)(y0 + ty + i*8) * C + x]);
  __syncthreads();
  int ox  = y0 + tx;
  int oy0 = blockIdx.x * 32;
  #pragma unroll
  for (int i = 0; i < 4; i++) out[(size_t)(oy0 + ty + i*8) * R + ox] = tile[tx][ty + i*8];
}

// ---------------- async global->LDS, 16B per lane ----------------
// dest: wave-uniform LDS base, HW writes base + lane*16 (linear).
// src:  per-lane global address (gather OK).
__device__ __forceinline__ void gload16(const void* g, void* l){
  __builtin_amdgcn_global_load_lds((const __attribute__((address_space(1))) void*)g,
                                   (__attribute__((address_space(3))) void*)l,
                                   16, 0, 0);
}

// ---------------- fused GEMM (bf16 MFMA, fp32 epilogue) ----------------
// MODE 0: A = [obj_b | attr_b]               (K=2048), out = relu(A@W+b)+attr_f
// MODE 1: A = [obj_b[s] | rela_b | obj_b[o]] (K=3072), out = (relu(A@W+b)+rela_f)*mask
// Staging via global_load_lds dwordx4, linear LDS [128][64] bf16.
// Bank-conflict fix (rule 21: both-sides-or-neither): LDS slot s of row r holds
// global slot s^(r&7) (inverse-swizzled SOURCE address), reads XOR the same
// pattern back. DMA writes are linear (conflict-free); swizzled reads spread
// the 16 fragment-rows across all 8 bank-groups.
template<int MODE>
__global__ void gemm_fused(const unsigned short* __restrict__ objb,
                           const unsigned short* __restrict__ xresb,
                           const float* __restrict__ xresf,
                           const int* __restrict__ edges,
                           const float* __restrict__ mask,
                           const unsigned short* __restrict__ WT,
                           const float* __restrict__ bias,
                           float* __restrict__ out)
{
  constexpr int K = MODE ? 3*D_ : 2*D_;
  __shared__ unsigned short Asm[128*64];        // 16 KB, linear, LDA=64
  __shared__ unsigned short Bsm[128*64];        // 16 KB

  const int t  = threadIdx.x;
  const int l  = t & 63;
  const int w  = t >> 6;
  const int wr = w >> 1, wc = w & 1;            // 2x2 wave grid, 64x64 each
  const int m0 = blockIdx.y * 128;
  const int n0 = blockIdx.x * 128;

  // staging: issue i covers rows [i*32 + w*8, +8); lane l -> row +(l>>3), LDS slot (l&7).
  // source slot is XOR-swizzled so LDS[r][s] = global[r][s ^ (r&7)]  (r&7 == l>>3).
  const int srow = (w << 3) + (l >> 3);             // 0..31 within each 32-row stripe
  const int gsl  = (((l & 7) ^ (l >> 3)) << 3);     // element offset of swizzled 16B slot

  const unsigned short* aA0[4];
  const unsigned short* aA1[4];
  const unsigned short* aA2[4];
  #pragma unroll
  for (int i = 0; i < 4; i++){
    int m = m0 + i*32 + srow;
    if (MODE == 0){
      aA0[i] = objb  + (size_t)m * D_ + gsl;          // obj half
      aA1[i] = xresb + (size_t)m * D_ + gsl;          // attr half
      aA2[i] = aA1[i];                                // unused
    } else {
      int b = m >> 9;                                 // m / NR_
      int s = edges[2*m];
      int o = edges[2*m + 1];
      aA0[i] = objb  + (size_t)((b << 8) + s) * D_ + gsl;   // b*NO_ + s
      aA1[i] = xresb + (size_t)m * D_ + gsl;                // rela_bf16
      aA2[i] = objb  + (size_t)((b << 8) + o) * D_ + gsl;
    }
  }
  const unsigned short* pB[4];
  #pragma unroll
  for (int i = 0; i < 4; i++) pB[i] = WT + (size_t)(n0 + i*32 + srow) * K + gsl;

  f32x4 acc[4][4];
  #pragma unroll
  for (int x = 0; x < 4; x++)
    #pragma unroll
    for (int y = 0; y < 4; y++) acc[x][y] = (f32x4){0.f,0.f,0.f,0.f};

  const int fr   = l & 15;                      // fragment row/col
  const int kqb  = (l >> 4) << 4;               // byte offset of lane-quad's 8 elems
  const int rxor = (l & 7) << 4;                // read-side swizzle (frag row &7 == l&7)

  for (int k0 = 0; k0 < K; k0 += 64){
    #pragma unroll
    for (int i = 0; i < 4; i++){
      const unsigned short* ga;
      if (MODE == 0){
        ga = (k0 < D_) ? aA0[i] + k0 : aA1[i] + (k0 - D_);
      } else {
        ga = (k0 < D_)   ? aA0[i] + k0
           : (k0 < 2*D_) ? aA1[i] + (k0 - D_)
           :               aA2[i] + (k0 - 2*D_);
      }
      gload16(ga,         &Asm[(i*32 + (w << 3)) * 64]);
      gload16(pB[i] + k0, &Bsm[(i*32 + (w << 3)) * 64]);
    }
    __syncthreads();   // drains vmcnt(0): DMA'd tiles visible

    #pragma unroll
    for (int ks = 0; ks < 2; ks++){
      bf16x8 af[4], bfv[4];
      #pragma unroll
      for (int x = 0; x < 4; x++){
        const int R = wr*64 + x*16 + fr;
        af[x]  = *(const bf16x8*)((const char*)Asm + R*128 + ((ks*64 + kqb) ^ rxor));
      }
      #pragma unroll
      for (int y = 0; y < 4; y++){
        const int RB = wc*64 + y*16 + fr;
        bfv[y] = *(const bf16x8*)((const char*)Bsm + RB*128 + ((ks*64 + kqb) ^ rxor));
      }
      #pragma unroll
      for (int x = 0; x < 4; x++)
        #pragma unroll
        for (int y = 0; y < 4; y++)
          acc[x][y] = __builtin_amdgcn_mfma_f32_16x16x32_bf16(af[x], bfv[y], acc[x][y], 0, 0, 0);
    }
    __syncthreads();
  }

  // epilogue: bias + relu + fp32 residual (+ mask), fp32 out
  const int colb = n0 + wc*64 + fr;
  float bv[4];
  #pragma unroll
  for (int y = 0; y < 4; y++) bv[y] = bias[colb + y*16];

  const int rowb = m0 + wr*64 + ((l >> 4) << 2);
  #pragma unroll
  for (int x = 0; x < 4; x++){
    #pragma unroll
    for (int i = 0; i < 4; i++){
      int gr = rowb + x*16 + i;
      float mk = 1.f;
      if (MODE == 1) mk = mask[gr];
      size_t rbase = (size_t)gr * D_;
      #pragma unroll
      for (int y = 0; y < 4; y++){
        int gc = colb + y*16;
        float v = acc[x][y][i] + bv[y];
        v = fmaxf(v, 0.f) + xresf[rbase + gc];
        if (MODE == 1) v *= mk;
        out[rbase + gc] = v;
      }
    }
  }
}

extern "C" void kernel_launch(void* const* d_in, const int* in_sizes, int n_in,
                              void* d_out, int out_size, void* d_ws, size_t ws_size,
                              hipStream_t stream){
  const float* obj   = (const float*)d_in[0];
  const float* attr  = (const float*)d_in[1];
  const float* rela  = (const float*)d_in[2];
  const int*   edges = (const int*)d_in[3];
  const float* masks = (const float*)d_in[4];
  const float* Wa    = (const float*)d_in[5];
  const float* ba    = (const float*)d_in[6];
  const float* Wr    = (const float*)d_in[7];
  const float* br    = (const float*)d_in[8];

  const size_t NOBJ  = (size_t)B_*NO_*D_;   // 33,554,432
  const size_t NRELA = (size_t)B_*NR_*D_;   // 67,108,864

  float* out0 = (float*)d_out;
  float* out1 = out0 + NOBJ;
  float* out2 = out1 + NOBJ;

  // bf16 scratch carved out of d_out regions (stream-ordered lifetimes):
  //   out0 region: obj_bf16 (64MB) + attr_bf16 (64MB)  — consumed by gemm0/gemm1, then overwritten by final obj copy
  //   out1 region: rela_bf16 (128MB)                    — consumed by gemm1, then overwritten by gemm0's output
  unsigned short* objb  = (unsigned short*)d_out;
  unsigned short* attrb = objb + NOBJ;
  unsigned short* relab = (unsigned short*)(out1);
  // W transposes (bf16) in ws: 4MB + 6MB
  unsigned short* WTa = (unsigned short*)d_ws;            // [1024][2048]
  unsigned short* WTr = WTa + (size_t)1024*2048;          // [1024][3072]

  conv_f32_bf16<<<(int)(NOBJ/8/256),  256, 0, stream>>>((const float4*)obj,  (uint4*)objb,  (int)(NOBJ/8));
  conv_f32_bf16<<<(int)(NOBJ/8/256),  256, 0, stream>>>((const float4*)attr, (uint4*)attrb, (int)(NOBJ/8));
  conv_f32_bf16<<<(int)(NRELA/8/256), 256, 0, stream>>>((const float4*)rela, (uint4*)relab, (int)(NRELA/8));

  transpose_f32_bf16<<<dim3(1024/32, 2048/32), dim3(32,8), 0, stream>>>(Wa, WTa, 2048, 1024);
  transpose_f32_bf16<<<dim3(1024/32, 3072/32), dim3(32,8), 0, stream>>>(Wr, WTr, 3072, 1024);

  // gemm1 FIRST (reads relab in out1 region), then gemm0 (overwrites out1), then obj copy (overwrites out0 scratch)
  gemm_fused<1><<<dim3(8, (B_*NR_)/128), 256, 0, stream>>>(objb, relab, rela, edges, masks, WTr, br, out2);
  gemm_fused<0><<<dim3(8, (B_*NO_)/128), 256, 0, stream>>>(objb, attrb, attr, nullptr, nullptr, WTa, ba, out1);

  int nv = (int)(NOBJ / 4);                                // uint4 = 4 floats
  copy_vec4<<<nv/256, 256, 0, stream>>>((const uint4*)obj, (uint4*)out0, nv);
}

// Round 2
// 1462.037 us; speedup vs baseline: 1.1468x; 1.0436x over previous
//
#include <hip/hip_runtime.h>

#define B_   128
#define NO_  256
#define NR_  512
#define D_   1024

typedef __bf16 bf16x8 __attribute__((ext_vector_type(8)));
typedef float  f32x4  __attribute__((ext_vector_type(4)));

__device__ __forceinline__ unsigned short f2b(float f){   // fp32 -> bf16 RNE
  unsigned int u = __float_as_uint(f);
  unsigned int r = (u + 0x7fffu + ((u >> 16) & 1u)) >> 16;
  return (unsigned short)r;
}

// ---------------- fp32 -> bf16 flat convert (8 elems/thread) ----------------
__global__ void conv_f32_bf16(const float4* __restrict__ in, uint4* __restrict__ out, int n8){
  int i = blockIdx.x * blockDim.x + threadIdx.x;
  if (i >= n8) return;
  float4 a = in[2*i], b = in[2*i+1];
  union { unsigned short s[8]; uint4 v; } p;
  p.s[0]=f2b(a.x); p.s[1]=f2b(a.y); p.s[2]=f2b(a.z); p.s[3]=f2b(a.w);
  p.s[4]=f2b(b.x); p.s[5]=f2b(b.y); p.s[6]=f2b(b.z); p.s[7]=f2b(b.w);
  out[i] = p.v;
}

// ---------------- copy fp32 obj -> out0 (uint4 = 4 floats) ----------------
__global__ void copy_vec4(const uint4* __restrict__ in, uint4* __restrict__ out, int n){
  int i = blockIdx.x * blockDim.x + threadIdx.x;
  if (i < n) out[i] = in[i];
}

// ---------------- transpose + convert: fp32 [R][C] -> bf16 [C][R] ----------------
__global__ void transpose_f32_bf16(const float* __restrict__ in,
                                   unsigned short* __restrict__ out, int R, int C){
  __shared__ unsigned short tile[32][33];
  int tx = threadIdx.x, ty = threadIdx.y;       // 32 x 8
  int x  = blockIdx.x * 32 + tx;
  int y0 = blockIdx.y * 32;
  #pragma unroll
  for (int i = 0; i < 4; i++) tile[ty + i*8][tx] = f2b(in[(size_t)(y0 + ty + i*8) * C + x]);
  __syncthreads();
  int ox  = y0 + tx;
  int oy0 = blockIdx.x * 32;
  #pragma unroll
  for (int i = 0; i < 4; i++) out[(size_t)(oy0 + ty + i*8) * R + ox] = tile[tx][ty + i*8];
}

// ---------------- async global->LDS, 16B per lane ----------------
__device__ __forceinline__ void gload16(const void* g, void* l){
  __builtin_amdgcn_global_load_lds((const __attribute__((address_space(1))) void*)g,
                                   (__attribute__((address_space(3))) void*)l,
                                   16, 0, 0);
}

// ---------------- fused GEMM: 256x256 tile, 8-wave, 8-phase counted-vmcnt ----------------
// MODE 0: A = [obj_b | attr_b]               (K=2048), out = relu(A@W+b)+attr_f
// MODE 1: A = [obj_b[s] | rela_b | obj_b[o]] (K=3072), out = (relu(A@W+b)+rela_f)*mask
// LDS: A/B each [2 buf][2 half][128][64] bf16 = 128 KB total, linear rows (128B).
// Swizzle (rule 21): LDS[r][slot] = global[r][slot ^ (r&7)] via pre-swizzled SOURCE
// address; reads XOR the same pattern. DMA dest stays linear. (verified round 1: 0 conflicts)
// Schedule per K-tile t (4 phases, raw s_barrier, counted vmcnt — never drain-0):
//   P1: read A[qm0](8) + B[qn0](4); stage (t+1).A1 -> nxt ; bar; MFMA(0,0); bar
//   P2: read B[qn1](4)            ; stage (t+1).B0 -> nxt ; bar; MFMA(0,1); bar
//   P3: read A[qm1](8)            ; stage (t+1).B1 -> nxt ; bar; MFMA(1,1); bar
//   P4:                             stage (t+2).A0 -> cur ; MFMA(1,0); vmcnt(2); bar
// Retire proof: cur.A-half is last read at P3 (qm1), cur.B-halves at P2 -> the only
// cur-targeting stage (P4, A0) sits behind P3's barrier. vmcnt(2) leaves exactly the
// (t+2).A0 pair in flight; everything tile t+1 needs has landed before its P1.
template<int MODE>
__global__ __launch_bounds__(512, 2)
void gemm_fused(const unsigned short* __restrict__ objb,
                const unsigned short* __restrict__ xresb,
                const float* __restrict__ xresf,
                const int* __restrict__ edges,
                const float* __restrict__ mask,
                const unsigned short* __restrict__ WT,
                const float* __restrict__ bias,
                float* __restrict__ out)
{
  constexpr int K  = MODE ? 3*D_ : 2*D_;
  constexpr int NT = K / 64;

  __shared__ unsigned short Asm[2][2][128*64];  // 64 KB
  __shared__ unsigned short Bsm[2][2][128*64];  // 64 KB

  const int t  = threadIdx.x;
  const int l  = t & 63;
  const int w  = t >> 6;                        // wave 0..7
  const int wr = w >> 2;                        // 0..1  (M)
  const int wc = w & 3;                         // 0..3  (N)

  // T1: XCD-aware bijective swizzle (nwg % 8 == 0). Consecutive lin share the
  // A-panel (4 n-blocks) and land on one XCD's L2.
  const int q8  = gridDim.x >> 3;
  const int lin = (blockIdx.x & 7) * q8 + (blockIdx.x >> 3);
  const int m0  = (lin >> 2) * 256;             // N/256 = 4 n-blocks
  const int n0  = (lin & 3) * 256;

  // staging coords: thread t -> row (t>>3) within a 64-row round, swizzled 16B slot
  const int trow = t >> 3;                      // 0..63
  const int gsl  = (((t & 7) ^ (trow & 7)) << 3);

  // per-(half,round) source row offsets (u32 element offsets)
  unsigned int offA0[4], offA1[4], offA2[4], offB[4];
  #pragma unroll
  for (int h = 0; h < 2; h++){
    #pragma unroll
    for (int r = 0; r < 2; r++){
      const int hr = h*2 + r;
      const int m  = m0 + h*128 + r*64 + trow;
      if (MODE == 0){
        offA0[hr] = (unsigned)m * D_ + gsl;
        offA1[hr] = offA0[hr];
        offA2[hr] = 0;
      } else {
        const int b = m >> 9;                   // m / NR_
        const int s = edges[2*m], o = edges[2*m+1];
        offA0[hr] = (unsigned)((b << 8) + s) * D_ + gsl;  // b*NO_ + s
        offA1[hr] = (unsigned)m * D_ + gsl;               // rela
        offA2[hr] = (unsigned)((b << 8) + o) * D_ + gsl;
      }
      const int n = n0 + h*128 + r*64 + trow;
      offB[hr] = (unsigned)n * K + gsl;
    }
  }

#define STAGE_A(tile, half) do{                                               \
    const int _tl = (tile); const int _k = _tl*64; const int _b = _tl & 1;    \
    const unsigned short *_g0, *_g1;                                          \
    if (MODE == 0){                                                           \
      if (_k < D_){ _g0 = objb  + offA0[(half)*2+0] + _k;                     \
                    _g1 = objb  + offA0[(half)*2+1] + _k; }                   \
      else        { _g0 = xresb + offA1[(half)*2+0] + (_k - D_);              \
                    _g1 = xresb + offA1[(half)*2+1] + (_k - D_); }            \
    } else {                                                                  \
      if (_k < D_){ _g0 = objb  + offA0[(half)*2+0] + _k;                     \
                    _g1 = objb  + offA0[(half)*2+1] + _k; }                   \
      else if (_k < 2*D_){ _g0 = xresb + offA1[(half)*2+0] + (_k - D_);       \
                           _g1 = xresb + offA1[(half)*2+1] + (_k - D_); }     \
      else        { _g0 = objb  + offA2[(half)*2+0] + (_k - 2*D_);            \
                    _g1 = objb  + offA2[(half)*2+1] + (_k - 2*D_); }          \
    }                                                                         \
    gload16(_g0, &Asm[_b][half][(w*8     ) * 64]);                            \
    gload16(_g1, &Asm[_b][half][(w*8 + 64) * 64]);                            \
  }while(0)

#define STAGE_B(tile, half) do{                                               \
    const int _tl = (tile); const int _k = _tl*64; const int _b = _tl & 1;    \
    gload16(WT + offB[(half)*2+0] + _k, &Bsm[_b][half][(w*8     ) * 64]);     \
    gload16(WT + offB[(half)*2+1] + _k, &Bsm[_b][half][(w*8 + 64) * 64]);     \
  }while(0)

  f32x4 acc[8][4];
  #pragma unroll
  for (int X = 0; X < 8; X++)
    #pragma unroll
    for (int Y = 0; Y < 4; Y++) acc[X][Y] = (f32x4){0.f,0.f,0.f,0.f};

  const int fr  = l & 15;
  const int swz = (fr & 7) << 4;                // read-side XOR (matches source swizzle)
  const int rdo = (l >> 4) << 4;                // lane-quad byte offset

  auto lda = [&](int buf, int qm, int x, int kh) -> bf16x8 {
    const int r = qm*64 + x*16 + fr;            // row within half `wr`
    return *(const bf16x8*)((const char*)&Asm[buf][wr][r*64] + ((kh*64 + rdo) ^ swz));
  };
  auto ldb = [&](int buf, int qn, int y, int kh) -> bf16x8 {
    const int r = (wc & 1)*64 + qn*32 + y*16 + fr;
    return *(const bf16x8*)((const char*)&Bsm[buf][wc>>1][r*64] + ((kh*64 + rdo) ^ swz));
  };

  bf16x8 af[4][2], bq0[2][2], bq1[2][2];

#define MFMA16(qm, qn, BQ)                                                    \
  __builtin_amdgcn_s_setprio(1);                                              \
  _Pragma("unroll")                                                           \
  for (int x = 0; x < 4; x++){                                                \
    _Pragma("unroll")                                                         \
    for (int y = 0; y < 2; y++){                                              \
      acc[(qm)*4+x][(qn)*2+y] = __builtin_amdgcn_mfma_f32_16x16x32_bf16(      \
          af[x][0], BQ[y][0], acc[(qm)*4+x][(qn)*2+y], 0, 0, 0);              \
      acc[(qm)*4+x][(qn)*2+y] = __builtin_amdgcn_mfma_f32_16x16x32_bf16(      \
          af[x][1], BQ[y][1], acc[(qm)*4+x][(qn)*2+y], 0, 0, 0);              \
    }                                                                         \
  }                                                                           \
  __builtin_amdgcn_s_setprio(0);

  // prologue: tile0 fully + (1).A0 riding; wait leaves exactly those 2 in flight
  STAGE_A(0,0); STAGE_A(0,1); STAGE_B(0,0); STAGE_B(0,1);
  STAGE_A(1,0);
  asm volatile("s_waitcnt vmcnt(2)" ::: "memory");
  __builtin_amdgcn_s_barrier();

  for (int tt = 0; tt < NT; ++tt){
    const int cur = tt & 1;
    // P1
    #pragma unroll
    for (int x = 0; x < 4; x++){ af[x][0] = lda(cur,0,x,0); af[x][1] = lda(cur,0,x,1); }
    #pragma unroll
    for (int y = 0; y < 2; y++){ bq0[y][0] = ldb(cur,0,y,0); bq0[y][1] = ldb(cur,0,y,1); }
    if (tt+1 < NT) STAGE_A(tt+1, 1);
    __builtin_amdgcn_s_barrier();
    MFMA16(0,0,bq0)
    __builtin_amdgcn_s_barrier();
    // P2
    #pragma unroll
    for (int y = 0; y < 2; y++){ bq1[y][0] = ldb(cur,1,y,0); bq1[y][1] = ldb(cur,1,y,1); }
    if (tt+1 < NT) STAGE_B(tt+1, 0);
    __builtin_amdgcn_s_barrier();
    MFMA16(0,1,bq1)
    __builtin_amdgcn_s_barrier();
    // P3
    #pragma unroll
    for (int x = 0; x < 4; x++){ af[x][0] = lda(cur,1,x,0); af[x][1] = lda(cur,1,x,1); }
    if (tt+1 < NT) STAGE_B(tt+1, 1);
    __builtin_amdgcn_s_barrier();
    MFMA16(1,1,bq1)
    __builtin_amdgcn_s_barrier();
    // P4: stage (t+2).A0 into cur (A-half regions retired after P3's barrier)
    if (tt+2 < NT) STAGE_A(tt+2, 0);
    MFMA16(1,0,bq0)
    asm volatile("s_waitcnt vmcnt(2)" ::: "memory");
    __builtin_amdgcn_s_barrier();
  }
#undef STAGE_A
#undef STAGE_B
#undef MFMA16

  // epilogue: bias + relu + fp32 residual (+ mask), fp32 out
  const int colb = n0 + wc*64 + fr;
  float bv[4];
  #pragma unroll
  for (int Y = 0; Y < 4; Y++) bv[Y] = bias[colb + Y*16];

  const int rowq = (l >> 4) << 2;
  #pragma unroll
  for (int X = 0; X < 8; X++){
    #pragma unroll
    for (int i = 0; i < 4; i++){
      const int gr = m0 + wr*128 + X*16 + rowq + i;
      float mk = 1.f;
      if (MODE == 1) mk = mask[gr];
      const size_t rbase = (size_t)gr * D_;
      #pragma unroll
      for (int Y = 0; Y < 4; Y++){
        const int gc = colb + Y*16;
        float v = acc[X][Y][i] + bv[Y];
        v = fmaxf(v, 0.f) + xresf[rbase + gc];
        if (MODE == 1) v *= mk;
        out[rbase + gc] = v;
      }
    }
  }
}

extern "C" void kernel_launch(void* const* d_in, const int* in_sizes, int n_in,
                              void* d_out, int out_size, void* d_ws, size_t ws_size,
                              hipStream_t stream){
  const float* obj   = (const float*)d_in[0];
  const float* attr  = (const float*)d_in[1];
  const float* rela  = (const float*)d_in[2];
  const int*   edges = (const int*)d_in[3];
  const float* masks = (const float*)d_in[4];
  const float* Wa    = (const float*)d_in[5];
  const float* ba    = (const float*)d_in[6];
  const float* Wr    = (const float*)d_in[7];
  const float* br    = (const float*)d_in[8];

  const size_t NOBJ  = (size_t)B_*NO_*D_;   // 33,554,432
  const size_t NRELA = (size_t)B_*NR_*D_;   // 67,108,864

  float* out0 = (float*)d_out;
  float* out1 = out0 + NOBJ;
  float* out2 = out1 + NOBJ;

  // bf16 scratch carved out of d_out regions (stream-ordered lifetimes):
  //   out0 region: obj_bf16 + attr_bf16 — consumed by gemms, then overwritten by final obj copy
  //   out1 region: rela_bf16            — consumed by gemm1, then overwritten by gemm0's output
  unsigned short* objb  = (unsigned short*)d_out;
  unsigned short* attrb = objb + NOBJ;
  unsigned short* relab = (unsigned short*)(out1);
  // W transposes (bf16) in ws: 4MB + 6MB
  unsigned short* WTa = (unsigned short*)d_ws;            // [1024][2048]
  unsigned short* WTr = WTa + (size_t)1024*2048;          // [1024][3072]

  conv_f32_bf16<<<(int)(NOBJ/8/256),  256, 0, stream>>>((const float4*)obj,  (uint4*)objb,  (int)(NOBJ/8));
  conv_f32_bf16<<<(int)(NOBJ/8/256),  256, 0, stream>>>((const float4*)attr, (uint4*)attrb, (int)(NOBJ/8));
  conv_f32_bf16<<<(int)(NRELA/8/256), 256, 0, stream>>>((const float4*)rela, (uint4*)relab, (int)(NRELA/8));

  transpose_f32_bf16<<<dim3(1024/32, 2048/32), dim3(32,8), 0, stream>>>(Wa, WTa, 2048, 1024);
  transpose_f32_bf16<<<dim3(1024/32, 3072/32), dim3(32,8), 0, stream>>>(Wr, WTr, 3072, 1024);

  // gemm1 FIRST (reads relab in out1 region), then gemm0 (overwrites out1), then obj copy
  gemm_fused<1><<<(B_*NR_/256)*(D_/256), 512, 0, stream>>>(objb, relab, rela, edges, masks, WTr, br, out2);
  gemm_fused<0><<<(B_*NO_/256)*(D_/256), 512, 0, stream>>>(objb, attrb, attr, nullptr, nullptr, WTa, ba, out1);

  int nv = (int)(NOBJ / 4);                                // uint4 = 4 floats
  copy_vec4<<<nv/256, 256, 0, stream>>>((const uint4*)obj, (uint4*)out0, nv);
}